// Round 4
// baseline (432.976 us; speedup 1.0000x reference)
//
#include <hip/hip_runtime.h>
#include <math.h>

#define N_NODES 100000
#define N_EDGES 1600000
#define D_IN 256
#define D_OUT 128

// ---- workspace layout (bytes) ------------------------------------------
// support : float[N_NODES*D_OUT]             @ 0           (51,200,000)
// counts  : int[N_NODES+1] (-> offsets)      @ 51,200,000  (   400,004)
// csr_ev  : int2[N_EDGES] {col, val-bits}    @ 51,600,008  (12,800,000)
// bsums   : int[SCAN_BLOCKS]                 @ 64,400,008
// pos_e   : int[N_EDGES] lives in d_out (free until agg overwrites it)
#define OFF_SUPPORT 0
#define OFF_COUNTS  51200000
#define OFF_CSREV   51600008
#define OFF_BSUMS   64400008

#define SCAN_CHUNK  1024
#define SCAN_BLOCKS ((N_NODES + SCAN_CHUNK - 1) / SCAN_CHUNK)  // 98

#define GB 128                                   // GEMM block tile (nodes)
#define GEMM_BLOCKS ((N_NODES + GB - 1) / GB)    // 782
#define GEMM_SPLIT  391                          // half in K1, half in K2
#define EDGE_BLOCKS ((N_EDGES + 255) / 256)      // 6250

#define AP 40   // LDS row pitch in shorts: 32 k + 8 pad (2-way banks = free)

typedef __attribute__((ext_vector_type(8))) short s8v;   // 8 bf16 = 4 VGPR
typedef __attribute__((ext_vector_type(4))) float f4v;   // mfma acc

__device__ __forceinline__ short f2bf(float x) {   // RNE fp32 -> bf16 bits
  unsigned u = __float_as_uint(x);
  unsigned r = u + 0x7FFF + ((u >> 16) & 1);
  return (short)(r >> 16);
}
__device__ __forceinline__ float bf2f(short h) {
  return __uint_as_float(((unsigned)(unsigned short)h) << 16);
}

// ---------------------------------------------------------------------------
// Split-bf16 MFMA GEMM: support = X*W + b.
// x = hi + lo (two bf16); D = Ahi*Bhi + Ahi*Blo + Alo*Bhi (fp32 acc),
// residual ~2^-16 rel -> fp32-equivalent for this tolerance.
// Block: 256 thr = 4 waves; tile 128 nodes x 128 feats, BK=32.
// Wave w owns rows [w*32, w*32+32): 2 m-tiles x 8 n-tiles of 16x16x32 MFMA.
// ---------------------------------------------------------------------------
__device__ __forceinline__ void gemm_body(
    int gb, const float* __restrict__ input, const float* __restrict__ W,
    const float* __restrict__ b, float* __restrict__ support) {
  __shared__ short Ahi[GB * AP];   // [row][k] 128x40
  __shared__ short Alo[GB * AP];
  __shared__ short Bhi[D_OUT * AP];  // transposed: [n][k] 128x40
  __shared__ short Blo[D_OUT * AP];

  const int t = threadIdx.x;
  const int node0 = gb * GB;
  const int lane = t & 63;
  const int wv = t >> 6;          // wave 0..3
  const int qm = lane & 15;       // m (A) / n (B) / col (C)
  const int quad = lane >> 4;     // k-group (operands) / row-group (C)

  f4v acc[2][8];
#pragma unroll
  for (int mt = 0; mt < 2; mt++)
#pragma unroll
    for (int nt = 0; nt < 8; nt++) acc[mt][nt] = (f4v){0.f, 0.f, 0.f, 0.f};

  for (int k0 = 0; k0 < D_IN; k0 += 32) {
    // ---- stage A: 128 rows x 32 k, fp32 -> (hi,lo) bf16 ----
#pragma unroll
    for (int j = 0; j < 4; j++) {
      int i = t + j * 256;        // 0..1023 float4s
      int row = i >> 3;           // 0..127
      int kf = (i & 7) << 2;      // 0,4,...,28
      int node = node0 + row;
      float4 v = make_float4(0.f, 0.f, 0.f, 0.f);
      if (node < N_NODES)
        v = *(const float4*)(input + (size_t)node * D_IN + k0 + kf);
      short4 h, l;
      h.x = f2bf(v.x); l.x = f2bf(v.x - bf2f(h.x));
      h.y = f2bf(v.y); l.y = f2bf(v.y - bf2f(h.y));
      h.z = f2bf(v.z); l.z = f2bf(v.z - bf2f(h.z));
      h.w = f2bf(v.w); l.w = f2bf(v.w - bf2f(h.w));
      *(short4*)&Ahi[row * AP + kf] = h;
      *(short4*)&Alo[row * AP + kf] = l;
    }
    // ---- stage B transposed: W[k][n] -> Bt[n][k], 32 k x 128 n ----
#pragma unroll
    for (int j = 0; j < 4; j++) {
      int i = t + j * 256;        // 0..1023 float4s
      int kk = i >> 5;            // 0..31
      int nf = (i & 31) << 2;     // 0,4,...,124
      float4 v = *(const float4*)(W + (size_t)(k0 + kk) * D_OUT + nf);
      float vv[4] = {v.x, v.y, v.z, v.w};
#pragma unroll
      for (int c = 0; c < 4; c++) {
        short h = f2bf(vv[c]);
        Bhi[(nf + c) * AP + kk] = h;
        Blo[(nf + c) * AP + kk] = f2bf(vv[c] - bf2f(h));
      }
    }
    __syncthreads();

    // ---- MFMA: 2 m-tiles x 8 n-tiles x 3 split-products ----
    s8v ah0 = *(s8v*)&Ahi[(wv * 32 + qm) * AP + quad * 8];
    s8v al0 = *(s8v*)&Alo[(wv * 32 + qm) * AP + quad * 8];
    s8v ah1 = *(s8v*)&Ahi[(wv * 32 + 16 + qm) * AP + quad * 8];
    s8v al1 = *(s8v*)&Alo[(wv * 32 + 16 + qm) * AP + quad * 8];
#pragma unroll
    for (int nt = 0; nt < 8; nt++) {
      s8v bh = *(s8v*)&Bhi[(nt * 16 + qm) * AP + quad * 8];
      s8v bl = *(s8v*)&Blo[(nt * 16 + qm) * AP + quad * 8];
      acc[0][nt] = __builtin_amdgcn_mfma_f32_16x16x32_bf16(ah0, bh, acc[0][nt], 0, 0, 0);
      acc[0][nt] = __builtin_amdgcn_mfma_f32_16x16x32_bf16(ah0, bl, acc[0][nt], 0, 0, 0);
      acc[0][nt] = __builtin_amdgcn_mfma_f32_16x16x32_bf16(al0, bh, acc[0][nt], 0, 0, 0);
      acc[1][nt] = __builtin_amdgcn_mfma_f32_16x16x32_bf16(ah1, bh, acc[1][nt], 0, 0, 0);
      acc[1][nt] = __builtin_amdgcn_mfma_f32_16x16x32_bf16(ah1, bl, acc[1][nt], 0, 0, 0);
      acc[1][nt] = __builtin_amdgcn_mfma_f32_16x16x32_bf16(al1, bh, acc[1][nt], 0, 0, 0);
    }
    __syncthreads();
  }

  // ---- epilogue: C/D layout col=lane&15, row=quad*4+reg; add bias ----
  float bias[8];
#pragma unroll
  for (int nt = 0; nt < 8; nt++) bias[nt] = b[nt * 16 + qm];
#pragma unroll
  for (int mt = 0; mt < 2; mt++) {
#pragma unroll
    for (int nt = 0; nt < 8; nt++) {
      int col = nt * 16 + qm;
#pragma unroll
      for (int r = 0; r < 4; r++) {
        int node = node0 + wv * 32 + mt * 16 + quad * 4 + r;
        if (node < N_NODES)
          support[(size_t)node * D_OUT + col] = acc[mt][nt][r] + bias[nt];
      }
    }
  }
}

// K1: GEMM part A  ||  hist (degree count + per-edge position)
__global__ __launch_bounds__(256) void gemm_hist_kernel(
    const float* __restrict__ input, const float* __restrict__ W,
    const float* __restrict__ b, float* __restrict__ support,
    const int* __restrict__ erow, int* __restrict__ counts,
    int* __restrict__ pos_e) {
  if (blockIdx.x < GEMM_SPLIT) {
    gemm_body(blockIdx.x, input, W, b, support);
  } else {
    int e = (blockIdx.x - GEMM_SPLIT) * 256 + threadIdx.x;
    if (e < N_EDGES) pos_e[e] = atomicAdd(&counts[erow[e]], 1);
  }
}

// K2: GEMM part B  ||  build (atomic-free bucket scatter of packed int2)
__global__ __launch_bounds__(256) void gemm_build_kernel(
    const float* __restrict__ input, const float* __restrict__ W,
    const float* __restrict__ b, float* __restrict__ support,
    const int* __restrict__ erow, const int* __restrict__ ecol,
    const float* __restrict__ eval, const int* __restrict__ offsets,
    const int* __restrict__ pos_e, int2* __restrict__ csr_ev) {
  if (blockIdx.x < GEMM_BLOCKS - GEMM_SPLIT) {
    gemm_body(blockIdx.x + GEMM_SPLIT, input, W, b, support);
  } else {
    int e = (blockIdx.x - (GEMM_BLOCKS - GEMM_SPLIT)) * 256 + threadIdx.x;
    if (e < N_EDGES) {
      int idx = offsets[erow[e]] + pos_e[e];
      csr_ev[idx] = make_int2(ecol[e], __float_as_int(eval[e]));
    }
  }
}

// ---------------------------------------------------------------------------
// 3-phase exclusive scan over counts (verified round 2)
// ---------------------------------------------------------------------------
__global__ __launch_bounds__(256) void scan_phase1(const int* __restrict__ counts,
                                                   int* __restrict__ bsums) {
  __shared__ int ts[256];
  int t = threadIdx.x;
  int idx0 = blockIdx.x * SCAN_CHUNK + t * 4;
  int s = 0;
#pragma unroll
  for (int i = 0; i < 4; i++)
    if (idx0 + i < N_NODES) s += counts[idx0 + i];
  ts[t] = s;
  __syncthreads();
#pragma unroll
  for (int off = 128; off > 0; off >>= 1) {
    if (t < off) ts[t] += ts[t + off];
    __syncthreads();
  }
  if (t == 0) bsums[blockIdx.x] = ts[0];
}

__global__ __launch_bounds__(128) void scan_phase2(int* __restrict__ bsums) {
  __shared__ int s[128];
  int t = threadIdx.x;
  int v = (t < SCAN_BLOCKS) ? bsums[t] : 0;
  s[t] = v;
  __syncthreads();
#pragma unroll
  for (int off = 1; off < 128; off <<= 1) {
    int x = (t >= off) ? s[t - off] : 0;
    __syncthreads();
    s[t] += x;
    __syncthreads();
  }
  if (t < SCAN_BLOCKS) bsums[t] = s[t] - v;  // exclusive
}

__global__ __launch_bounds__(256) void scan_phase3(int* __restrict__ counts,
                                                   const int* __restrict__ bsums) {
  __shared__ int ts[256];
  int t = threadIdx.x;
  int b = blockIdx.x;
  int idx0 = b * SCAN_CHUNK + t * 4;
  int v[4];
  int s = 0;
#pragma unroll
  for (int i = 0; i < 4; i++) {
    v[i] = (idx0 + i < N_NODES) ? counts[idx0 + i] : 0;
    s += v[i];
  }
  ts[t] = s;
  __syncthreads();
#pragma unroll
  for (int off = 1; off < 256; off <<= 1) {
    int x = (t >= off) ? ts[t - off] : 0;
    __syncthreads();
    ts[t] += x;
    __syncthreads();
  }
  int run = bsums[b] + ts[t] - s;
#pragma unroll
  for (int i = 0; i < 4; i++) {
    int idx = idx0 + i;
    if (idx < N_NODES) counts[idx] = run;
    run += v[i];
  }
  if (b == 0 && t == 0) counts[N_NODES] = N_EDGES;
}

// ---------------------------------------------------------------------------
// Gather-aggregate + fused tanh, 4x unrolled for MLP (verified round 3)
// ---------------------------------------------------------------------------
__global__ __launch_bounds__(128) void agg_kernel(
    const int* __restrict__ offsets, const int2* __restrict__ csr_ev,
    const float* __restrict__ support, float* __restrict__ out) {
  int r = blockIdx.x;
  int f = threadIdx.x;
  int beg = offsets[r];
  int end = offsets[r + 1];
  float acc = 0.f;
  int j = beg;
  for (; j + 4 <= end; j += 4) {
    int2 e0 = csr_ev[j + 0];
    int2 e1 = csr_ev[j + 1];
    int2 e2 = csr_ev[j + 2];
    int2 e3 = csr_ev[j + 3];
    float s0 = support[(size_t)e0.x * D_OUT + f];
    float s1 = support[(size_t)e1.x * D_OUT + f];
    float s2 = support[(size_t)e2.x * D_OUT + f];
    float s3 = support[(size_t)e3.x * D_OUT + f];
    acc = fmaf(__int_as_float(e0.y), s0, acc);
    acc = fmaf(__int_as_float(e1.y), s1, acc);
    acc = fmaf(__int_as_float(e2.y), s2, acc);
    acc = fmaf(__int_as_float(e3.y), s3, acc);
  }
  for (; j < end; j++) {
    int2 ev = csr_ev[j];
    acc = fmaf(__int_as_float(ev.y), support[(size_t)ev.x * D_OUT + f], acc);
  }
  out[(size_t)r * D_OUT + f] = tanhf(acc);
}

extern "C" void kernel_launch(void* const* d_in, const int* in_sizes, int n_in,
                              void* d_out, int out_size, void* d_ws, size_t ws_size,
                              hipStream_t stream) {
  const float* input = (const float*)d_in[0];
  const int* erow = (const int*)d_in[1];
  const int* ecol = (const int*)d_in[2];
  const float* eval = (const float*)d_in[3];
  const float* W = (const float*)d_in[4];
  const float* b = (const float*)d_in[5];
  float* out = (float*)d_out;

  char* ws = (char*)d_ws;
  float* support = (float*)(ws + OFF_SUPPORT);
  int* counts = (int*)(ws + OFF_COUNTS);  // becomes offsets after scan
  int2* csr_ev = (int2*)(ws + OFF_CSREV);
  int* bsums = (int*)(ws + OFF_BSUMS);
  int* pos_e = (int*)d_out;  // d_out as scratch; agg overwrites it last

  hipMemsetAsync(ws + OFF_COUNTS, 0, (size_t)(N_NODES + 1) * 4, stream);

  // K1: MFMA-GEMM part A || histogram (per-edge position into d_out scratch)
  hipLaunchKernelGGL(gemm_hist_kernel, dim3(GEMM_SPLIT + EDGE_BLOCKS), dim3(256),
                     0, stream, input, W, b, support, erow, counts, pos_e);
  // exclusive scan: counts -> offsets
  hipLaunchKernelGGL(scan_phase1, dim3(SCAN_BLOCKS), dim3(256), 0, stream,
                     counts, bsums);
  hipLaunchKernelGGL(scan_phase2, dim3(1), dim3(128), 0, stream, bsums);
  hipLaunchKernelGGL(scan_phase3, dim3(SCAN_BLOCKS), dim3(256), 0, stream,
                     counts, bsums);
  // K2: MFMA-GEMM part B || atomic-free CSR bucket scatter
  hipLaunchKernelGGL(gemm_build_kernel,
                     dim3((GEMM_BLOCKS - GEMM_SPLIT) + EDGE_BLOCKS), dim3(256),
                     0, stream, input, W, b, support, erow, ecol, eval, counts,
                     pos_e, csr_ev);
  // out = tanh(A_csr * support)
  hipLaunchKernelGGL(agg_kernel, dim3(N_NODES), dim3(128), 0, stream, counts,
                     csr_ev, support, out);
}

// Round 5
// 420.677 us; speedup vs baseline: 1.0292x; 1.0292x over previous
//
#include <hip/hip_runtime.h>
#include <math.h>

#define N_NODES 100000
#define N_EDGES 1600000
#define D_IN 256
#define D_OUT 128

// ---- workspace layout (bytes) ------------------------------------------
// support : float[N_NODES*D_OUT]             @ 0           (51,200,000)
// counts  : int[N_NODES+1] (-> offsets)      @ 51,200,000  (   400,004)
// csr_ev  : int2[N_EDGES] {col, val-bits}    @ 51,600,008  (12,800,000)
// bsums   : int[SCAN_BLOCKS]                 @ 64,400,008  (       392)
// wt_hi   : short[128*256] W^T bf16-hi       @ 64,400,416  (    65,536)
// wt_lo   : short[128*256] W^T bf16-lo       @ 64,465,952  (    65,536)
// pos_e   : int[N_EDGES] lives in d_out (free until agg overwrites it)
#define OFF_SUPPORT 0
#define OFF_COUNTS  51200000
#define OFF_CSREV   51600008
#define OFF_BSUMS   64400008
#define OFF_WTHI    64400416
#define OFF_WTLO    64465952

#define SCAN_CHUNK  1024
#define SCAN_BLOCKS ((N_NODES + SCAN_CHUNK - 1) / SCAN_CHUNK)  // 98

#define GB 128                                   // GEMM block tile (nodes)
#define GEMM_BLOCKS ((N_NODES + GB - 1) / GB)    // 782
#define EDGE_BLOCKS ((N_EDGES + 255) / 256)      // 6250

#define AP 40   // LDS row pitch in shorts: 32 k + 8 pad

typedef __attribute__((ext_vector_type(8))) short s8v;   // 8 bf16 = 4 VGPR
typedef __attribute__((ext_vector_type(4))) float f4v;   // mfma acc

__device__ __forceinline__ short f2bf(float x) {   // RNE fp32 -> bf16 bits
  unsigned u = __float_as_uint(x);
  unsigned r = u + 0x7FFF + ((u >> 16) & 1);
  return (short)(r >> 16);
}
__device__ __forceinline__ float bf2f(short h) {
  return __uint_as_float(((unsigned)(unsigned short)h) << 16);
}

// ---------------------------------------------------------------------------
// K0: W[k][n] fp32 -> wt_hi/wt_lo[n][k] bf16 split (once; 32K elems)
// ---------------------------------------------------------------------------
__global__ __launch_bounds__(256) void wconv_kernel(
    const float* __restrict__ W, short* __restrict__ wt_hi,
    short* __restrict__ wt_lo) {
  int idx = blockIdx.x * 256 + threadIdx.x;   // grid 128 -> 32768
  int k = idx >> 7;
  int n = idx & 127;
  float v = W[idx];
  short h = f2bf(v);
  wt_hi[n * 256 + k] = h;
  wt_lo[n * 256 + k] = f2bf(v - bf2f(h));
}

// ---------------------------------------------------------------------------
// Split-bf16 MFMA GEMM body (verified round 4): support = X*W + b.
// B staging now vector-copies pre-converted wt tiles (no per-block convert).
// ---------------------------------------------------------------------------
__device__ __forceinline__ void gemm_body(
    int gb, const float* __restrict__ input, const short* __restrict__ wt_hi,
    const short* __restrict__ wt_lo, const float* __restrict__ b,
    float* __restrict__ support) {
  __shared__ short Ahi[GB * AP];
  __shared__ short Alo[GB * AP];
  __shared__ short Bhi[D_OUT * AP];
  __shared__ short Blo[D_OUT * AP];

  const int t = threadIdx.x;
  const int node0 = gb * GB;
  const int lane = t & 63;
  const int wv = t >> 6;
  const int qm = lane & 15;
  const int quad = lane >> 4;

  f4v acc[2][8];
#pragma unroll
  for (int mt = 0; mt < 2; mt++)
#pragma unroll
    for (int nt = 0; nt < 8; nt++) acc[mt][nt] = (f4v){0.f, 0.f, 0.f, 0.f};

  for (int k0 = 0; k0 < D_IN; k0 += 32) {
    // ---- stage A: 128 rows x 32 k, fp32 -> (hi,lo) bf16 ----
#pragma unroll
    for (int j = 0; j < 4; j++) {
      int i = t + j * 256;
      int row = i >> 3;
      int kf = (i & 7) << 2;
      int node = node0 + row;
      float4 v = make_float4(0.f, 0.f, 0.f, 0.f);
      if (node < N_NODES)
        v = *(const float4*)(input + (size_t)node * D_IN + k0 + kf);
      short4 h, l;
      h.x = f2bf(v.x); l.x = f2bf(v.x - bf2f(h.x));
      h.y = f2bf(v.y); l.y = f2bf(v.y - bf2f(h.y));
      h.z = f2bf(v.z); l.z = f2bf(v.z - bf2f(h.z));
      h.w = f2bf(v.w); l.w = f2bf(v.w - bf2f(h.w));
      *(short4*)&Ahi[row * AP + kf] = h;
      *(short4*)&Alo[row * AP + kf] = l;
    }
    // ---- stage B: straight 16B copy of pre-converted wt tiles ----
#pragma unroll
    for (int j = 0; j < 2; j++) {
      int i = t + j * 256;        // 0..511
      int n = i >> 2;             // 0..127
      int kq = (i & 3) << 3;      // 0,8,16,24
      *(s8v*)&Bhi[n * AP + kq] = *(const s8v*)&wt_hi[n * 256 + k0 + kq];
      *(s8v*)&Blo[n * AP + kq] = *(const s8v*)&wt_lo[n * 256 + k0 + kq];
    }
    __syncthreads();

    s8v ah0 = *(s8v*)&Ahi[(wv * 32 + qm) * AP + quad * 8];
    s8v al0 = *(s8v*)&Alo[(wv * 32 + qm) * AP + quad * 8];
    s8v ah1 = *(s8v*)&Ahi[(wv * 32 + 16 + qm) * AP + quad * 8];
    s8v al1 = *(s8v*)&Alo[(wv * 32 + 16 + qm) * AP + quad * 8];
#pragma unroll
    for (int nt = 0; nt < 8; nt++) {
      s8v bh = *(s8v*)&Bhi[(nt * 16 + qm) * AP + quad * 8];
      s8v bl = *(s8v*)&Blo[(nt * 16 + qm) * AP + quad * 8];
      acc[0][nt] = __builtin_amdgcn_mfma_f32_16x16x32_bf16(ah0, bh, acc[0][nt], 0, 0, 0);
      acc[0][nt] = __builtin_amdgcn_mfma_f32_16x16x32_bf16(ah0, bl, acc[0][nt], 0, 0, 0);
      acc[0][nt] = __builtin_amdgcn_mfma_f32_16x16x32_bf16(al0, bh, acc[0][nt], 0, 0, 0);
      acc[1][nt] = __builtin_amdgcn_mfma_f32_16x16x32_bf16(ah1, bh, acc[1][nt], 0, 0, 0);
      acc[1][nt] = __builtin_amdgcn_mfma_f32_16x16x32_bf16(ah1, bl, acc[1][nt], 0, 0, 0);
      acc[1][nt] = __builtin_amdgcn_mfma_f32_16x16x32_bf16(al1, bh, acc[1][nt], 0, 0, 0);
    }
    __syncthreads();
  }

  float bias[8];
#pragma unroll
  for (int nt = 0; nt < 8; nt++) bias[nt] = b[nt * 16 + qm];
#pragma unroll
  for (int mt = 0; mt < 2; mt++) {
#pragma unroll
    for (int nt = 0; nt < 8; nt++) {
      int col = nt * 16 + qm;
#pragma unroll
      for (int r = 0; r < 4; r++) {
        int node = node0 + wv * 32 + mt * 16 + quad * 4 + r;
        if (node < N_NODES)
          support[(size_t)node * D_OUT + col] = acc[mt][nt][r] + bias[nt];
      }
    }
  }
}

// K1: FULL GEMM || FULL hist (GEMM blocks first to seed the CUs)
__global__ __launch_bounds__(256) void gemm_hist_kernel(
    const float* __restrict__ input, const short* __restrict__ wt_hi,
    const short* __restrict__ wt_lo, const float* __restrict__ b,
    float* __restrict__ support, const int* __restrict__ erow,
    int* __restrict__ counts, int* __restrict__ pos_e) {
  if (blockIdx.x < GEMM_BLOCKS) {
    gemm_body(blockIdx.x, input, wt_hi, wt_lo, b, support);
  } else {
    int e = (blockIdx.x - GEMM_BLOCKS) * 256 + threadIdx.x;
    if (e < N_EDGES) pos_e[e] = atomicAdd(&counts[erow[e]], 1);
  }
}

// K2: atomic-free CSR bucket scatter
__global__ __launch_bounds__(256) void build_kernel(
    const int* __restrict__ erow, const int* __restrict__ ecol,
    const float* __restrict__ eval, const int* __restrict__ offsets,
    const int* __restrict__ pos_e, int2* __restrict__ csr_ev) {
  int e = blockIdx.x * 256 + threadIdx.x;
  if (e < N_EDGES) {
    int idx = offsets[erow[e]] + pos_e[e];
    csr_ev[idx] = make_int2(ecol[e], __float_as_int(eval[e]));
  }
}

// ---------------------------------------------------------------------------
// 3-phase exclusive scan over counts (verified round 2)
// ---------------------------------------------------------------------------
__global__ __launch_bounds__(256) void scan_phase1(const int* __restrict__ counts,
                                                   int* __restrict__ bsums) {
  __shared__ int ts[256];
  int t = threadIdx.x;
  int idx0 = blockIdx.x * SCAN_CHUNK + t * 4;
  int s = 0;
#pragma unroll
  for (int i = 0; i < 4; i++)
    if (idx0 + i < N_NODES) s += counts[idx0 + i];
  ts[t] = s;
  __syncthreads();
#pragma unroll
  for (int off = 128; off > 0; off >>= 1) {
    if (t < off) ts[t] += ts[t + off];
    __syncthreads();
  }
  if (t == 0) bsums[blockIdx.x] = ts[0];
}

__global__ __launch_bounds__(128) void scan_phase2(int* __restrict__ bsums) {
  __shared__ int s[128];
  int t = threadIdx.x;
  int v = (t < SCAN_BLOCKS) ? bsums[t] : 0;
  s[t] = v;
  __syncthreads();
#pragma unroll
  for (int off = 1; off < 128; off <<= 1) {
    int x = (t >= off) ? s[t - off] : 0;
    __syncthreads();
    s[t] += x;
    __syncthreads();
  }
  if (t < SCAN_BLOCKS) bsums[t] = s[t] - v;  // exclusive
}

__global__ __launch_bounds__(256) void scan_phase3(int* __restrict__ counts,
                                                   const int* __restrict__ bsums) {
  __shared__ int ts[256];
  int t = threadIdx.x;
  int b = blockIdx.x;
  int idx0 = b * SCAN_CHUNK + t * 4;
  int v[4];
  int s = 0;
#pragma unroll
  for (int i = 0; i < 4; i++) {
    v[i] = (idx0 + i < N_NODES) ? counts[idx0 + i] : 0;
    s += v[i];
  }
  ts[t] = s;
  __syncthreads();
#pragma unroll
  for (int off = 1; off < 256; off <<= 1) {
    int x = (t >= off) ? ts[t - off] : 0;
    __syncthreads();
    ts[t] += x;
    __syncthreads();
  }
  int run = bsums[b] + ts[t] - s;
#pragma unroll
  for (int i = 0; i < 4; i++) {
    int idx = idx0 + i;
    if (idx < N_NODES) counts[idx] = run;
    run += v[i];
  }
  if (b == 0 && t == 0) counts[N_NODES] = N_EDGES;
}

// ---------------------------------------------------------------------------
// Gather-aggregate + fused tanh, 8x unrolled (MLP to hide HBM latency)
// ---------------------------------------------------------------------------
__global__ __launch_bounds__(128) void agg_kernel(
    const int* __restrict__ offsets, const int2* __restrict__ csr_ev,
    const float* __restrict__ support, float* __restrict__ out) {
  int r = blockIdx.x;
  int f = threadIdx.x;
  int beg = offsets[r];
  int end = offsets[r + 1];
  float acc = 0.f;
  int j = beg;
  for (; j + 8 <= end; j += 8) {
    int2 e[8];
    float s[8];
#pragma unroll
    for (int u = 0; u < 8; u++) e[u] = csr_ev[j + u];
#pragma unroll
    for (int u = 0; u < 8; u++) s[u] = support[(size_t)e[u].x * D_OUT + f];
#pragma unroll
    for (int u = 0; u < 8; u++) acc = fmaf(__int_as_float(e[u].y), s[u], acc);
  }
  for (; j < end; j++) {
    int2 ev = csr_ev[j];
    acc = fmaf(__int_as_float(ev.y), support[(size_t)ev.x * D_OUT + f], acc);
  }
  out[(size_t)r * D_OUT + f] = tanhf(acc);
}

extern "C" void kernel_launch(void* const* d_in, const int* in_sizes, int n_in,
                              void* d_out, int out_size, void* d_ws, size_t ws_size,
                              hipStream_t stream) {
  const float* input = (const float*)d_in[0];
  const int* erow = (const int*)d_in[1];
  const int* ecol = (const int*)d_in[2];
  const float* eval = (const float*)d_in[3];
  const float* W = (const float*)d_in[4];
  const float* b = (const float*)d_in[5];
  float* out = (float*)d_out;

  char* ws = (char*)d_ws;
  float* support = (float*)(ws + OFF_SUPPORT);
  int* counts = (int*)(ws + OFF_COUNTS);  // becomes offsets after scan
  int2* csr_ev = (int2*)(ws + OFF_CSREV);
  int* bsums = (int*)(ws + OFF_BSUMS);
  short* wt_hi = (short*)(ws + OFF_WTHI);
  short* wt_lo = (short*)(ws + OFF_WTLO);
  int* pos_e = (int*)d_out;  // d_out as scratch; agg overwrites it last

  // K0: convert W once (transposed bf16 hi/lo)
  hipLaunchKernelGGL(wconv_kernel, dim3((D_IN * D_OUT) / 256), dim3(256), 0,
                     stream, W, wt_hi, wt_lo);
  hipMemsetAsync(ws + OFF_COUNTS, 0, (size_t)(N_NODES + 1) * 4, stream);

  // K1: full MFMA-GEMM || full histogram
  hipLaunchKernelGGL(gemm_hist_kernel, dim3(GEMM_BLOCKS + EDGE_BLOCKS),
                     dim3(256), 0, stream, input, wt_hi, wt_lo, b, support,
                     erow, counts, pos_e);
  // exclusive scan: counts -> offsets
  hipLaunchKernelGGL(scan_phase1, dim3(SCAN_BLOCKS), dim3(256), 0, stream,
                     counts, bsums);
  hipLaunchKernelGGL(scan_phase2, dim3(1), dim3(128), 0, stream, bsums);
  hipLaunchKernelGGL(scan_phase3, dim3(SCAN_BLOCKS), dim3(256), 0, stream,
                     counts, bsums);
  // K2: atomic-free CSR bucket scatter
  hipLaunchKernelGGL(build_kernel, dim3(EDGE_BLOCKS), dim3(256), 0, stream,
                     erow, ecol, eval, counts, pos_e, csr_ev);
  // out = tanh(A_csr * support)
  hipLaunchKernelGGL(agg_kernel, dim3(N_NODES), dim3(128), 0, stream, counts,
                     csr_ev, support, out);
}